// Round 5
// baseline (120.804 us; speedup 1.0000x reference)
//
#include <hip/hip_runtime.h>
#include <math.h>

// Problem constants
#define BATCH 32
#define HHWW  12544          // 112*112
#define CH    96
#define CH4   24             // CH/4
#define CR    24             // reduced channels
#define NBLK  28             // slices per batch
#define ROWS_PER_BLK (HHWW / NBLK)   // 448
#define RDIM  16             // row-threads per block
#define SB    16             // batches per stage (77MB input chunk, fits L3)

typedef float f32x4 __attribute__((ext_vector_type(4)));

// ws layout:
//   partial [BATCH][NBLK][CH] f32   : 344064 B
//   gate    [BATCH][CH]       f32   :  12288 B  (offset 344064, 16B-aligned)
//   counter [BATCH]           u32   :    128 B  (offset 356352)

// ---------------------------------------------------------------------------
// Kernel P: pool partials + last-block-per-batch gate compute.
// grid = (NBLK, SB), block = (24,16) = 384 threads.
// Ticket trick: counter is never initialized (0xAA poison) and never reset.
// Each block does atomicAdd(+1); exactly one block in any 28 consecutive
// ticket values satisfies (old+1) % 28 == 0 -> that block computes the gate.
// Result is bit-identical regardless of which block runs it.
// ---------------------------------------------------------------------------
__global__ void __launch_bounds__(384)
se_pool_gate(const f32x4* __restrict__ in, int b0,
             const float* __restrict__ w_reduce,  // [CH][CR]
             const float* __restrict__ b_reduce,  // [CR]
             const float* __restrict__ w_expand,  // [CR][CH]
             const float* __restrict__ b_expand,  // [CH]
             float* __restrict__ partial,         // [BATCH][NBLK][CH]
             float* __restrict__ gate,            // [BATCH][CH]
             unsigned int* __restrict__ counter)  // [BATCH]
{
    const int blk = blockIdx.x;        // 0..27 slice
    const int b   = b0 + blockIdx.y;   // batch
    const int q   = threadIdx.x;       // 0..23 channel quad
    const int r   = threadIdx.y;       // 0..15 row lane
    const int tid = q + CH4 * r;       // 0..383

    const size_t boff = (size_t)b * (HHWW * CH4);
    const int row0 = blk * ROWS_PER_BLK;

    // ---- pooling partial sums (proven R2 body) ----
    f32x4 acc = (f32x4)(0.f);
    #pragma unroll 4
    for (int row = row0 + r; row < row0 + ROWS_PER_BLK; row += RDIM)
        acc += in[boff + (size_t)row * CH4 + q];

    __shared__ f32x4 sdata[RDIM][CH4];
    sdata[r][q] = acc;
    __syncthreads();
    if (r == 0) {
        f32x4 s = sdata[0][q];
        #pragma unroll
        for (int k = 1; k < RDIM; ++k) s += sdata[k][q];
        ((f32x4*)partial)[((size_t)b * NBLK + blk) * CH4 + q] = s;
    }
    // make this block's partial stores complete (vmcnt(0) before barrier)
    __syncthreads();

    // ---- last-block election (agent-scope release/acquire) ----
    __shared__ int isLast;
    if (tid == 0) {
        unsigned int old = __hip_atomic_fetch_add(&counter[b], 1u,
                                                  __ATOMIC_ACQ_REL,
                                                  __HIP_MEMORY_SCOPE_AGENT);
        isLast = (((old + 1u) % NBLK) == 0u) ? 1 : 0;
    }
    __syncthreads();

    if (isLast) {
        __threadfence();   // acquire belt-and-suspenders before reading partials
        __shared__ float pooled[CH];
        __shared__ float hsw[CR];

        if (tid < CH) {
            float s = 0.f;
            #pragma unroll
            for (int k = 0; k < NBLK; ++k)
                s += partial[((size_t)b * NBLK + k) * CH + tid];
            pooled[tid] = s * (1.0f / (float)HHWW);
        }
        __syncthreads();
        if (tid < CR) {
            float h = b_reduce[tid];
            #pragma unroll
            for (int i = 0; i < CH; ++i)
                h += pooled[i] * w_reduce[i * CR + tid];
            hsw[tid] = h / (1.0f + expf(-h));   // swish
        }
        __syncthreads();
        if (tid < CH) {
            float g = b_expand[tid];
            #pragma unroll
            for (int j = 0; j < CR; ++j)
                g += hsw[j] * w_expand[j * CH + tid];
            gate[(size_t)b * CH + tid] = 1.0f / (1.0f + expf(-g));
        }
    }
}

// ---------------------------------------------------------------------------
// Kernel S: scale one stage.  grid = (49, SB), block 256, 24 float4/thread.
// Reads hit L3 (stage input just streamed by P); NT stores to HBM.
// Channel-quad cycles with period 3 (256 % 24 == 16) -> 3 gate regs.
// ---------------------------------------------------------------------------
__global__ void __launch_bounds__(256)
se_scale(const f32x4* __restrict__ in, int b0,
         const float* __restrict__ gate,   // [BATCH][CH]
         f32x4* __restrict__ out)
{
    const int b = b0 + blockIdx.y;
    const int t = threadIdx.x;

    const int q0 = t % CH4;
    const int q1 = (q0 + 16) % CH4;
    const int q2 = (q0 + 8) % CH4;
    const f32x4* g4 = (const f32x4*)(gate + (size_t)b * CH);
    const f32x4 g0 = g4[q0];
    const f32x4 g1 = g4[q1];
    const f32x4 g2 = g4[q2];

    const size_t boff = (size_t)b * (HHWW * CH4);
    int idx = blockIdx.x * 6144 + t;
    #pragma unroll
    for (int k = 0; k < 24; k += 3) {
        f32x4 v0 = in[boff + idx];
        f32x4 v1 = in[boff + idx + 256];
        f32x4 v2 = in[boff + idx + 512];
        __builtin_nontemporal_store(v0 * g0, &out[boff + idx]);
        __builtin_nontemporal_store(v1 * g1, &out[boff + idx + 256]);
        __builtin_nontemporal_store(v2 * g2, &out[boff + idx + 512]);
        idx += 768;
    }
}

extern "C" void kernel_launch(void* const* d_in, const int* in_sizes, int n_in,
                              void* d_out, int out_size, void* d_ws, size_t ws_size,
                              hipStream_t stream) {
    const f32x4* in       = (const f32x4*)d_in[0];
    const float* w_reduce = (const float*)d_in[1];
    const float* b_reduce = (const float*)d_in[2];
    const float* w_expand = (const float*)d_in[3];
    const float* b_expand = (const float*)d_in[4];
    f32x4* out = (f32x4*)d_out;

    char* ws = (char*)d_ws;
    float*        partial = (float*)ws;                       // 344064 B
    float*        gate    = (float*)(ws + 344064);            //  12288 B
    unsigned int* counter = (unsigned int*)(ws + 356352);     //    128 B

    dim3 gridP(NBLK, SB);   // 448 blocks
    dim3 blockP(CH4, RDIM); // 384 threads
    dim3 gridS(49, SB);     // 784 blocks; 49*6144 f32x4 = per-batch count

    // Stage 0: batches 0..15
    se_pool_gate<<<gridP, blockP, 0, stream>>>(in, 0, w_reduce, b_reduce,
                                               w_expand, b_expand,
                                               partial, gate, counter);
    se_scale<<<gridS, 256, 0, stream>>>(in, 0, gate, out);

    // Stage 1: batches 16..31
    se_pool_gate<<<gridP, blockP, 0, stream>>>(in, SB, w_reduce, b_reduce,
                                               w_expand, b_expand,
                                               partial, gate, counter);
    se_scale<<<gridS, 256, 0, stream>>>(in, SB, gate, out);
}

// Round 7
// 116.211 us; speedup vs baseline: 1.0395x; 1.0395x over previous
//
#include <hip/hip_runtime.h>
#include <math.h>

// Problem constants
#define BATCH 32
#define HHWW  12544          // 112*112
#define CH    96
#define CH4   24             // CH/4
#define CR    24             // reduced channels
#define NBLK  28             // slices per batch
#define ROWS_PER_BLK (HHWW / NBLK)   // 448
#define RDIM  16             // row-threads per block

typedef float f32x4 __attribute__((ext_vector_type(4)));

// ws layout:
//   partial [BATCH][NBLK][CH] f32 : 344064 B
//   gate    [BATCH][CH]       f32 :  12288 B (offset 344064)
//   counter [BATCH]           u32 :   128 B (offset 356352)

// ---------------------------------------------------------------------------
// Kernel 1: pool partials + last-block-per-batch gate (ticket election).
// grid = (NBLK, BATCH) = 896 blocks, block (24,16) = 384 threads.
// counter is never initialized/reset (0xAA poison is fine): any 28 consecutive
// ticket values contain (old+1) % 28 == 0 exactly once, so exactly one block
// per batch per launch computes the gate — deterministic regardless of which.
// PROVEN correct in R5.
// ---------------------------------------------------------------------------
__global__ void __launch_bounds__(384)
se_pool_gate(const f32x4* __restrict__ in,
             const float* __restrict__ w_reduce,  // [CH][CR]
             const float* __restrict__ b_reduce,  // [CR]
             const float* __restrict__ w_expand,  // [CR][CH]
             const float* __restrict__ b_expand,  // [CH]
             float* __restrict__ partial,         // [BATCH][NBLK][CH]
             float* __restrict__ gate,            // [BATCH][CH]
             unsigned int* __restrict__ counter)  // [BATCH]
{
    const int blk = blockIdx.x;   // 0..27 slice
    const int b   = blockIdx.y;   // 0..31 batch
    const int q   = threadIdx.x;  // 0..23 channel quad
    const int r   = threadIdx.y;  // 0..15 row lane
    const int tid = q + CH4 * r;  // 0..383

    const size_t boff = (size_t)b * (HHWW * CH4);
    const int row0 = blk * ROWS_PER_BLK;

    // ---- pooling partial sums (normal loads: keep input L3-resident) ----
    f32x4 acc = (f32x4)(0.f);
    #pragma unroll 4
    for (int row = row0 + r; row < row0 + ROWS_PER_BLK; row += RDIM)
        acc += in[boff + (size_t)row * CH4 + q];

    __shared__ f32x4 sdata[RDIM][CH4];
    sdata[r][q] = acc;
    __syncthreads();
    if (r == 0) {
        f32x4 s = sdata[0][q];
        #pragma unroll
        for (int k = 1; k < RDIM; ++k) s += sdata[k][q];
        ((f32x4*)partial)[((size_t)b * NBLK + blk) * CH4 + q] = s;
    }
    __syncthreads();

    // ---- last-block election (agent-scope release/acquire) ----
    __shared__ int isLast;
    if (tid == 0) {
        unsigned int old = __hip_atomic_fetch_add(&counter[b], 1u,
                                                  __ATOMIC_ACQ_REL,
                                                  __HIP_MEMORY_SCOPE_AGENT);
        isLast = (((old + 1u) % NBLK) == 0u) ? 1 : 0;
    }
    __syncthreads();

    if (isLast) {
        __threadfence();
        __shared__ float pooled[CH];
        __shared__ float hsw[CR];

        if (tid < CH) {
            float s = 0.f;
            #pragma unroll
            for (int k = 0; k < NBLK; ++k)
                s += partial[((size_t)b * NBLK + k) * CH + tid];
            pooled[tid] = s * (1.0f / (float)HHWW);
        }
        __syncthreads();
        if (tid < CR) {
            float h = b_reduce[tid];
            #pragma unroll
            for (int i = 0; i < CH; ++i)
                h += pooled[i] * w_reduce[i * CR + tid];
            hsw[tid] = h / (1.0f + expf(-h));   // swish
        }
        __syncthreads();
        if (tid < CH) {
            float g = b_expand[tid];
            #pragma unroll
            for (int j = 0; j < CR; ++j)
                g += hsw[j] * w_expand[j * CH + tid];
            gate[(size_t)b * CH + tid] = 1.0f / (1.0f + expf(-g));
        }
    }
}

// ---------------------------------------------------------------------------
// Kernel 2: scale. grid = (49, BATCH), block 256, 24 float4/thread.
// Channel-quad cycles with period 3 (256 % 24 == 16) -> 3 gate regs.
// Output via __builtin_nontemporal_store (coherent NT — PROVEN in R2).
// ---------------------------------------------------------------------------
__global__ void __launch_bounds__(256)
se_scale(const f32x4* __restrict__ in,
         const float* __restrict__ gate,   // [BATCH][CH]
         f32x4* __restrict__ out)
{
    const int b = blockIdx.y;
    const int t = threadIdx.x;

    const int q0 = t % CH4;
    const int q1 = (q0 + 16) % CH4;
    const int q2 = (q0 + 8) % CH4;
    const f32x4* g4 = (const f32x4*)(gate + (size_t)b * CH);
    const f32x4 g0 = g4[q0];
    const f32x4 g1 = g4[q1];
    const f32x4 g2 = g4[q2];

    const size_t boff = (size_t)b * (HHWW * CH4);
    int idx = blockIdx.x * 6144 + t;
    #pragma unroll
    for (int k = 0; k < 24; k += 3) {
        f32x4 v0 = in[boff + idx];
        f32x4 v1 = in[boff + idx + 256];
        f32x4 v2 = in[boff + idx + 512];
        __builtin_nontemporal_store(v0 * g0, &out[boff + idx]);
        __builtin_nontemporal_store(v1 * g1, &out[boff + idx + 256]);
        __builtin_nontemporal_store(v2 * g2, &out[boff + idx + 512]);
        idx += 768;
    }
}

extern "C" void kernel_launch(void* const* d_in, const int* in_sizes, int n_in,
                              void* d_out, int out_size, void* d_ws, size_t ws_size,
                              hipStream_t stream) {
    const f32x4* in       = (const f32x4*)d_in[0];
    const float* w_reduce = (const float*)d_in[1];
    const float* b_reduce = (const float*)d_in[2];
    const float* w_expand = (const float*)d_in[3];
    const float* b_expand = (const float*)d_in[4];
    f32x4* out = (f32x4*)d_out;

    char* ws = (char*)d_ws;
    float*        partial = (float*)ws;                    // 344064 B
    float*        gate    = (float*)(ws + 344064);         //  12288 B
    unsigned int* counter = (unsigned int*)(ws + 356352);  //    128 B

    dim3 gridP(NBLK, BATCH);    // 896 blocks
    dim3 blockP(CH4, RDIM);     // 384 threads
    se_pool_gate<<<gridP, blockP, 0, stream>>>(in, w_reduce, b_reduce,
                                               w_expand, b_expand,
                                               partial, gate, counter);

    dim3 gridS(49, BATCH);      // 1568 blocks
    se_scale<<<gridS, 256, 0, stream>>>(in, gate, out);
}

// Round 8
// 76.252 us; speedup vs baseline: 1.5843x; 1.5240x over previous
//
#include <hip/hip_runtime.h>
#include <hip/hip_cooperative_groups.h>
#include <math.h>

namespace cg = cooperative_groups;

// Problem constants
#define BATCH 32
#define HHWW  12544          // 112*112
#define CH    96
#define CH4   24             // CH/4
#define CR    24             // reduced channels
#define RDIM  16             // row-threads per block

// fused (cooperative) geometry
#define SLICES 32
#define RPS    (HHWW / SLICES)       // 392 rows per slice (not multiple of 16; loop handles)

// fallback (R2-proven) geometry
#define NBLK 28
#define ROWS_PER_BLK (HHWW / NBLK)   // 448

typedef float f32x4 __attribute__((ext_vector_type(4)));

// ws layout:
//   partial: fused uses [BATCH][SLICES][CH] = 393216 B ; fallback uses [BATCH][NBLK][CH] = 344064 B
//   gate (fallback only): offset 393216, 12288 B

// ===========================================================================
// COOPERATIVE single-pass kernel. grid (SLICES, BATCH) = 1024 blocks,
// block (24,16) = 384 threads. __launch_bounds__(384,8) caps VGPR at 64 so
// 5 blocks/CU fit -> 1280 >= 1024 co-residency. ONE grid.sync() pays the
// cross-XCD coherence cost once (vs 896 acq_rel flushes in R7 = disaster).
// ===========================================================================
__global__ void __launch_bounds__(384, 8)
se_fused(const f32x4* __restrict__ in,
         const float* __restrict__ w_reduce,   // [CH][CR]
         const float* __restrict__ b_reduce,   // [CR]
         const float* __restrict__ w_expand,   // [CR][CH]
         const float* __restrict__ b_expand,   // [CH]
         float* __restrict__ partial,          // [BATCH][SLICES][CH]
         f32x4* __restrict__ out) {
    const int blk = blockIdx.x;   // 0..31 slice
    const int b   = blockIdx.y;   // 0..31 batch
    const int q   = threadIdx.x;  // 0..23 channel quad
    const int r   = threadIdx.y;  // 0..15 row lane
    const int tid = q + CH4 * r;  // 0..383

    const size_t boff = (size_t)b * (HHWW * CH4);
    const int row0 = blk * RPS;

    // ---- phase 1: pooling partial sums (streaming read, ~24 waves/CU) ----
    f32x4 acc = (f32x4)(0.f);
    #pragma unroll 4
    for (int row = row0 + r; row < row0 + RPS; row += RDIM)
        acc += in[boff + (size_t)row * CH4 + q];

    __shared__ f32x4 sdata[RDIM][CH4];
    sdata[r][q] = acc;
    __syncthreads();
    if (r == 0) {
        f32x4 s = sdata[0][q];
        #pragma unroll
        for (int k = 1; k < RDIM; ++k) s += sdata[k][q];
        ((f32x4*)partial)[((size_t)b * SLICES + blk) * CH4 + q] = s;
    }

    cg::this_grid().sync();   // barrier + device-scope fence (once)

    // ---- phase 2: gate for batch b (redundant per block, tiny) ----
    __shared__ float pooled[CH];
    __shared__ float hsw[CR];
    __shared__ float gateS[CH];

    if (tid < CH) {
        float s = 0.f;
        #pragma unroll 4
        for (int k = 0; k < SLICES; ++k)
            s += partial[((size_t)b * SLICES + k) * CH + tid];
        pooled[tid] = s * (1.0f / (float)HHWW);
    }
    __syncthreads();
    if (tid < CR) {
        float h = b_reduce[tid];
        #pragma unroll
        for (int i = 0; i < CH; ++i)
            h += pooled[i] * w_reduce[i * CR + tid];
        hsw[tid] = h / (1.0f + expf(-h));   // swish
    }
    __syncthreads();
    if (tid < CH) {
        float g = b_expand[tid];
        #pragma unroll
        for (int j = 0; j < CR; ++j)
            g += hsw[j] * w_expand[j * CH + tid];
        gateS[tid] = 1.0f / (1.0f + expf(-g));
    }
    __syncthreads();

    // ---- phase 3: scale, same addresses as phase 1 (MALL-resident) ----
    const f32x4 g = ((const f32x4*)gateS)[q];
    #pragma unroll 4
    for (int row = row0 + r; row < row0 + RPS; row += RDIM) {
        const size_t off = boff + (size_t)row * CH4 + q;
        f32x4 v = in[off];
        __builtin_nontemporal_store(v * g, &out[off]);
    }
}

// ===========================================================================
// FALLBACK: verbatim R2 3-kernel path (proven 73.2 us).
// ===========================================================================
__global__ void se_pool_partial(const float* __restrict__ in,
                                float* __restrict__ partial) {
    const int b   = blockIdx.x;
    const int blk = blockIdx.y;
    const int q   = threadIdx.x;
    const int r   = threadIdx.y;

    const f32x4* inb = (const f32x4*)(in) + (size_t)b * HHWW * CH4;

    f32x4 acc = (f32x4)(0.f);
    const int row0 = blk * ROWS_PER_BLK;
    #pragma unroll 4
    for (int row = row0 + r; row < row0 + ROWS_PER_BLK; row += RDIM)
        acc += inb[(size_t)row * CH4 + q];

    __shared__ f32x4 sdata[RDIM][CH4];
    sdata[r][q] = acc;
    __syncthreads();
    if (r == 0) {
        f32x4 s = sdata[0][q];
        #pragma unroll
        for (int k = 1; k < RDIM; ++k) s += sdata[k][q];
        ((f32x4*)partial)[((size_t)b * NBLK + blk) * CH4 + q] = s;
    }
}

__global__ void se_gate(const float* __restrict__ partial,
                        const float* __restrict__ w_reduce,
                        const float* __restrict__ b_reduce,
                        const float* __restrict__ w_expand,
                        const float* __restrict__ b_expand,
                        float* __restrict__ gate) {
    const int b = blockIdx.x;
    const int c = threadIdx.x;

    __shared__ float pooled[CH];
    __shared__ float hsw[CR];

    float s = 0.f;
    #pragma unroll
    for (int k = 0; k < NBLK; ++k)
        s += partial[((size_t)b * NBLK + k) * CH + c];
    pooled[c] = s * (1.0f / (float)HHWW);
    __syncthreads();

    if (c < CR) {
        float h = b_reduce[c];
        #pragma unroll
        for (int i = 0; i < CH; ++i)
            h += pooled[i] * w_reduce[i * CR + c];
        hsw[c] = h / (1.0f + expf(-h));
    }
    __syncthreads();

    float g = b_expand[c];
    #pragma unroll
    for (int j = 0; j < CR; ++j)
        g += hsw[j] * w_expand[j * CH + c];
    gate[(size_t)b * CH + c] = 1.0f / (1.0f + expf(-g));
}

__global__ void __launch_bounds__(256)
se_scale(const f32x4* __restrict__ in,
         const float* __restrict__ gate,
         f32x4* __restrict__ out) {
    const int b = blockIdx.y;
    const int t = threadIdx.x;

    const int q0 = t % CH4;
    const int q1 = (q0 + 16) % CH4;
    const int q2 = (q0 + 8) % CH4;
    const f32x4* g4 = (const f32x4*)(gate + (size_t)b * CH);
    const f32x4 g0 = g4[q0];
    const f32x4 g1 = g4[q1];
    const f32x4 g2 = g4[q2];

    const size_t boff = (size_t)b * (HHWW * CH4);
    int idx = blockIdx.x * 6144 + t;
    #pragma unroll
    for (int k = 0; k < 24; k += 3) {
        f32x4 v0 = in[boff + idx];
        f32x4 v1 = in[boff + idx + 256];
        f32x4 v2 = in[boff + idx + 512];
        __builtin_nontemporal_store(v0 * g0, &out[boff + idx]);
        __builtin_nontemporal_store(v1 * g1, &out[boff + idx + 256]);
        __builtin_nontemporal_store(v2 * g2, &out[boff + idx + 512]);
        idx += 768;
    }
}

extern "C" void kernel_launch(void* const* d_in, const int* in_sizes, int n_in,
                              void* d_out, int out_size, void* d_ws, size_t ws_size,
                              hipStream_t stream) {
    const f32x4* in       = (const f32x4*)d_in[0];
    const float* w_reduce = (const float*)d_in[1];
    const float* b_reduce = (const float*)d_in[2];
    const float* w_expand = (const float*)d_in[3];
    const float* b_expand = (const float*)d_in[4];
    f32x4* out = (f32x4*)d_out;

    char* ws = (char*)d_ws;
    float* partial = (float*)ws;               // up to 393216 B
    float* gate    = (float*)(ws + 393216);    // 12288 B (fallback only)

    // Deterministic path choice: host-side occupancy query (capture-safe).
    int nb = 0;
    hipError_t e = hipOccupancyMaxActiveBlocksPerMultiprocessor(
                       &nb, reinterpret_cast<const void*>(se_fused), 384, 0);
    bool coop = (e == hipSuccess && nb >= 4);   // need 1024 blocks co-resident

    if (coop) {
        void* args[] = { (void*)&in, (void*)&w_reduce, (void*)&b_reduce,
                         (void*)&w_expand, (void*)&b_expand,
                         (void*)&partial, (void*)&out };
        dim3 grid(SLICES, BATCH);   // 1024 blocks
        dim3 block(CH4, RDIM);      // 384 threads
        e = hipLaunchCooperativeKernel((void*)se_fused, grid, block, args, 0, stream);
        if (e == hipSuccess) return;
    }

    // Fallback: proven R2 3-dispatch path.
    dim3 gridA(BATCH, NBLK);
    dim3 blockA(CH4, RDIM);
    se_pool_partial<<<gridA, blockA, 0, stream>>>((const float*)in, partial);

    se_gate<<<BATCH, CH, 0, stream>>>(partial, w_reduce, b_reduce,
                                      w_expand, b_expand, gate);

    dim3 gridC(49, BATCH);
    se_scale<<<gridC, 256, 0, stream>>>(in, gate, out);
}